// Round 5
// baseline (298.822 us; speedup 1.0000x reference)
//
#include <hip/hip_runtime.h>
#include <hip/hip_bf16.h>
#include <stdint.h>

// Problem constants
#define BATCH 64
#define IN_CAPS 512          // In (input capsules)
#define NCAP 16              // num_capsule
#define DCAP 64              // dim_capsule
#define GN (NCAP * DCAP)     // 1024
#define GM (BATCH * IN_CAPS) // 32768
#define GK 768               // input feature dim (K)

typedef __bf16 bf16;
typedef __attribute__((ext_vector_type(8))) __bf16 bf16x8;
typedef __attribute__((ext_vector_type(4))) __bf16 bf16x4;
typedef __attribute__((ext_vector_type(4))) float f32x4;

// async global->LDS 16B copy (wave-uniform LDS base + lane*16)
__device__ inline void async16(const bf16* g, bf16* l) {
    __builtin_amdgcn_global_load_lds(
        (__attribute__((address_space(1))) void*)g,
        (__attribute__((address_space(3))) void*)l, 16, 0, 0);
}

// ---------------------------------------------------------------------------
// Kernel 0: input dtype detection. flag=1 => inputs bf16, 0 => fp32.
// ---------------------------------------------------------------------------
__global__ void k_detect(const uint32_t* __restrict__ X32, int* __restrict__ flag) {
    const int lane = threadIdx.x; // 64 threads, 1 block
    int cnt = 0;
#pragma unroll
    for (int i = 0; i < 4; ++i) {
        const uint32_t w = X32[lane * 4 + i];
        const uint32_t e = (w >> 7) & 0xFF;
        cnt += (e >= 119 && e <= 130) ? 1 : 0;
    }
#pragma unroll
    for (int off = 32; off >= 1; off >>= 1) cnt += __shfl_xor(cnt, off);
    if (lane == 0) *flag = (cnt > 128) ? 1 : 0;
}

// 8-element loaders producing bf16x8 regardless of source dtype
__device__ inline bf16x8 load8(const bf16* p) { return *(const bf16x8*)p; }
__device__ inline bf16x8 load8(const float* p) {
    const f32x4 a = *(const f32x4*)p;
    const f32x4 b = *(const f32x4*)(p + 4);
    bf16x8 r;
    r[0] = (bf16)a[0]; r[1] = (bf16)a[1]; r[2] = (bf16)a[2]; r[3] = (bf16)a[3];
    r[4] = (bf16)b[0]; r[5] = (bf16)b[1]; r[6] = (bf16)b[2]; r[7] = (bf16)b[3];
    return r;
}

// ---------------------------------------------------------------------------
// Kernel 1: X -> bf16 (pure-BW pre-convert so GEMM can use global_load_lds)
// ---------------------------------------------------------------------------
template <typename T>
__global__ __launch_bounds__(256) void k_convX(const T* __restrict__ X,
                                               bf16* __restrict__ Xb,
                                               const int* __restrict__ flag, int want) {
    if (*flag != want) return;
    const size_t i = ((size_t)blockIdx.x * 256 + threadIdx.x) * 8;
    *(bf16x8*)(Xb + i) = load8(X + i);
}

// ---------------------------------------------------------------------------
// Kernel 2: transpose W [768][1024](T) -> Wt [1024][768] bf16 (K-contiguous).
// ---------------------------------------------------------------------------
template <typename T>
__global__ void k_transW(const T* __restrict__ W, bf16* __restrict__ Wt,
                         const int* __restrict__ flag, int want) {
    if (*flag != want) return;
    __shared__ bf16 t[32][33];
    const int k0 = blockIdx.x * 32;
    const int n0 = blockIdx.y * 32;
    const int tx = threadIdx.x, ty = threadIdx.y;
#pragma unroll
    for (int r = 0; r < 4; ++r)
        t[ty + r * 8][tx] = (bf16)(float)W[(size_t)(k0 + ty + r * 8) * GN + n0 + tx];
    __syncthreads();
#pragma unroll
    for (int r = 0; r < 4; ++r)
        Wt[(size_t)(n0 + ty + r * 8) * GK + k0 + tx] = t[tx][ty + r * 8];
}

// ---------------------------------------------------------------------------
// Kernel 3a: MFMA GEMM with async global->LDS staging (m97 rung). bf16 A/B.
//   LDS layout [row][32] identical to validated round-4 kernel; only the
//   staging path changed (global_load_lds dwordx4, no VGPR round-trip).
//   U: [b][cap][j][k] bf16   (b=m>>9, j=m&511, cap=n>>6, k=n&63)
// ---------------------------------------------------------------------------
__global__ __launch_bounds__(256) void k_gemm_async(const bf16* __restrict__ Xb,
                                                    const bf16* __restrict__ Wt,
                                                    bf16* __restrict__ U) {
    __shared__ bf16 sA[128 * 32]; // 8 KiB = 8 chunks of 1024 B
    __shared__ bf16 sB[128 * 32];

    const int tid = threadIdx.x;
    const int lane = tid & 63;
    const int wave = tid >> 6;
    const int wm = wave >> 1, wn = wave & 1;
    const int m0 = blockIdx.x * 128;
    const int n0 = blockIdx.y * 128;

    // async staging: wave w fills chunks {2w,2w+1} of sA and sB.
    // chunk c = rows 16c..16c+15; lane l -> row 16c+(l>>2), elem col (l&3)*8.
    const int c0 = wave * 2, c1 = wave * 2 + 1;
    const int rl = lane >> 2, cl = (lane & 3) * 8;
    const bf16* gA0 = Xb + (size_t)(m0 + c0 * 16 + rl) * GK + cl;
    const bf16* gA1 = Xb + (size_t)(m0 + c1 * 16 + rl) * GK + cl;
    const bf16* gB0 = Wt + (size_t)(n0 + c0 * 16 + rl) * GK + cl;
    const bf16* gB1 = Wt + (size_t)(n0 + c1 * 16 + rl) * GK + cl;
    bf16* lA0 = sA + c0 * 512; // wave-uniform chunk bases
    bf16* lA1 = sA + c1 * 512;
    bf16* lB0 = sB + c0 * 512;
    bf16* lB1 = sB + c1 * 512;

    f32x4 acc[4][4] = {};
    const int fr = lane & 15; // m (A) / n (B,D) within 16-tile
    const int fq = lane >> 4; // quad: k offset fq*8 (A/B), D row base fq*4

    for (int kt = 0; kt < GK / 32; ++kt) {
        __syncthreads(); // previous tile's LDS reads complete
        async16(gA0, lA0);
        async16(gA1, lA1);
        async16(gB0, lB0);
        async16(gB1, lB1);
        gA0 += 32; gA1 += 32; gB0 += 32; gB1 += 32;
        __syncthreads(); // barrier drain waits vmcnt(0): staged data visible

        bf16x8 af[4], bfr[4];
#pragma unroll
        for (int mi = 0; mi < 4; ++mi)
            af[mi] = *(const bf16x8*)(sA + (wm * 64 + mi * 16 + fr) * 32 + fq * 8);
#pragma unroll
        for (int ni = 0; ni < 4; ++ni)
            bfr[ni] = *(const bf16x8*)(sB + (wn * 64 + ni * 16 + fr) * 32 + fq * 8);
#pragma unroll
        for (int mi = 0; mi < 4; ++mi)
#pragma unroll
            for (int ni = 0; ni < 4; ++ni)
                acc[mi][ni] = __builtin_amdgcn_mfma_f32_16x16x32_bf16(
                    af[mi], bfr[ni], acc[mi][ni], 0, 0, 0);
    }

    // epilogue (validated): D col(n)=lane&15, row(m)=(lane>>4)*4+r
#pragma unroll
    for (int mi = 0; mi < 4; ++mi) {
#pragma unroll
        for (int ni = 0; ni < 4; ++ni) {
#pragma unroll
            for (int r = 0; r < 4; ++r) {
                const int m = m0 + wm * 64 + mi * 16 + fq * 4 + r;
                const int n = n0 + wn * 64 + ni * 16 + fr;
                const int bb = m >> 9, j = m & 511;
                const int ci = n >> 6, k = n & 63;
                U[(((size_t)(bb * NCAP + ci)) * IN_CAPS + j) * DCAP + k] =
                    (bf16)acc[mi][ni][r];
            }
        }
    }
}

// ---------------------------------------------------------------------------
// Kernel 3b: fallback GEMM (round-4 validated, inline conversion) — used only
// if ws_size can't hold Xb.
// ---------------------------------------------------------------------------
template <typename T>
__global__ __launch_bounds__(256) void k_gemm_inline(const T* __restrict__ X,
                                                     const bf16* __restrict__ Wt,
                                                     bf16* __restrict__ U,
                                                     const int* __restrict__ flag,
                                                     int want) {
    if (*flag != want) return;
    __shared__ bf16 sA[128 * 32];
    __shared__ bf16 sB[128 * 32];
    const int tid = threadIdx.x;
    const int lane = tid & 63;
    const int wave = tid >> 6;
    const int wm = wave >> 1, wn = wave & 1;
    const int m0 = blockIdx.x * 128;
    const int n0 = blockIdx.y * 128;
    const int srow = tid >> 2;
    const int scol = (tid & 3) * 8;
    f32x4 acc[4][4] = {};
    const int fr = lane & 15;
    const int fq = lane >> 4;
    for (int kt = 0; kt < GK / 32; ++kt) {
        const int kb = kt * 32;
        const bf16x8 a0 = load8(X + (size_t)(m0 + srow) * GK + kb + scol);
        const bf16x8 a1 = load8(X + (size_t)(m0 + srow + 64) * GK + kb + scol);
        const bf16x8 b0 = load8(Wt + (size_t)(n0 + srow) * GK + kb + scol);
        const bf16x8 b1 = load8(Wt + (size_t)(n0 + srow + 64) * GK + kb + scol);
        __syncthreads();
        *(bf16x8*)(sA + srow * 32 + scol) = a0;
        *(bf16x8*)(sA + (srow + 64) * 32 + scol) = a1;
        *(bf16x8*)(sB + srow * 32 + scol) = b0;
        *(bf16x8*)(sB + (srow + 64) * 32 + scol) = b1;
        __syncthreads();
        bf16x8 af[4], bfr[4];
#pragma unroll
        for (int mi = 0; mi < 4; ++mi)
            af[mi] = *(const bf16x8*)(sA + (wm * 64 + mi * 16 + fr) * 32 + fq * 8);
#pragma unroll
        for (int ni = 0; ni < 4; ++ni)
            bfr[ni] = *(const bf16x8*)(sB + (wn * 64 + ni * 16 + fr) * 32 + fq * 8);
#pragma unroll
        for (int mi = 0; mi < 4; ++mi)
#pragma unroll
            for (int ni = 0; ni < 4; ++ni)
                acc[mi][ni] = __builtin_amdgcn_mfma_f32_16x16x32_bf16(
                    af[mi], bfr[ni], acc[mi][ni], 0, 0, 0);
    }
#pragma unroll
    for (int mi = 0; mi < 4; ++mi) {
#pragma unroll
        for (int ni = 0; ni < 4; ++ni) {
#pragma unroll
            for (int r = 0; r < 4; ++r) {
                const int m = m0 + wm * 64 + mi * 16 + fq * 4 + r;
                const int n = n0 + wn * 64 + ni * 16 + fr;
                const int bb = m >> 9, j = m & 511;
                const int ci = n >> 6, k = n & 63;
                U[(((size_t)(bb * NCAP + ci)) * IN_CAPS + j) * DCAP + k] =
                    (bf16)acc[mi][ni][r];
            }
        }
    }
}

// ---------------------------------------------------------------------------
// Kernel 4: fused routing pass. Block per (b,cap). Stages the 512x64 U slice
// into LDS ONCE, then: out = squash(sum_j c[j]*u[j]),
// and (mode<2) logits bl[j] = <out, u[j]>.  mode: 0=first (c uniform),
// 1=mid, 2=final (write OutC, no logits).
// ---------------------------------------------------------------------------
__global__ __launch_bounds__(256) void k_route(const bf16* __restrict__ U,
                                               float* __restrict__ BL,
                                               float* __restrict__ OutC,
                                               int mode) {
    __shared__ bf16 su[IN_CAPS * DCAP]; // 64 KiB
    __shared__ float sc[IN_CAPS];       // 2 KiB
    __shared__ float red[16][64];       // 4 KiB
    __shared__ float sout[64];          // 256 B
    const int bi = blockIdx.x; // b*16 + cap
    const int tid = threadIdx.x;
    const size_t ubase = (size_t)bi * IN_CAPS * DCAP;

    // stage U slice: 64 KiB = 256 thr x 16 uint4
    {
        const uint4* g = (const uint4*)(U + ubase);
        uint4* s = (uint4*)su;
#pragma unroll
        for (int i = 0; i < 16; ++i) s[tid + i * 256] = g[tid + i * 256];
    }
    // stage c
    if (mode == 0) {
        sc[tid] = 0.0625f;
        sc[tid + 256] = 0.0625f;
    } else {
        sc[tid] = BL[(size_t)bi * IN_CAPS + tid];
        sc[tid + 256] = BL[(size_t)bi * IN_CAPS + tid + 256];
    }
    __syncthreads();

    const int lane = tid & 63, wave = tid >> 6;
    const int kq = lane & 15, jj = lane >> 4;

    // phase A: weighted sum over j
    float a0 = 0.f, a1 = 0.f, a2 = 0.f, a3 = 0.f;
#pragma unroll
    for (int it = 0; it < 32; ++it) {
        const int j = it * 16 + wave * 4 + jj;
        const bf16x4 v = *(const bf16x4*)(su + j * DCAP + kq * 4);
        const float cv = sc[j];
        a0 += cv * (float)v[0];
        a1 += cv * (float)v[1];
        a2 += cv * (float)v[2];
        a3 += cv * (float)v[3];
    }
    const int p = wave * 4 + jj;
    red[p][kq * 4 + 0] = a0;
    red[p][kq * 4 + 1] = a1;
    red[p][kq * 4 + 2] = a2;
    red[p][kq * 4 + 3] = a3;
    __syncthreads();

    if (wave == 0) {
        float s = 0.f;
#pragma unroll
        for (int q = 0; q < 16; ++q) s += red[q][lane];
        float ss = s * s;
#pragma unroll
        for (int off = 32; off >= 1; off >>= 1) ss += __shfl_xor(ss, off);
        const float val = s * rsqrtf(ss + 1e-7f);
        if (mode == 2) OutC[(size_t)bi * DCAP + lane] = val;
        sout[lane] = val;
    }
    if (mode == 2) return; // mode is block-uniform
    __syncthreads();

    // phase B: logits from LDS
    const float4 ov = *(const float4*)(sout + kq * 4);
#pragma unroll
    for (int it = 0; it < 32; ++it) {
        const int j = it * 16 + wave * 4 + jj;
        const bf16x4 v = *(const bf16x4*)(su + j * DCAP + kq * 4);
        float q = ov.x * (float)v[0] + ov.y * (float)v[1] +
                  ov.z * (float)v[2] + ov.w * (float)v[3];
        q += __shfl_xor(q, 1);
        q += __shfl_xor(q, 2);
        q += __shfl_xor(q, 4);
        q += __shfl_xor(q, 8);
        if (kq == 0) BL[(size_t)bi * IN_CAPS + j] = q;
    }
}

// ---------------------------------------------------------------------------
// Kernel 5: softmax over the 16-capsule axis, in place on BL.
// ---------------------------------------------------------------------------
__global__ __launch_bounds__(256) void k_softmax(float* __restrict__ BL) {
    const int t = blockIdx.x * 256 + threadIdx.x;
    const int b = t >> 9, j = t & 511;
    float* p = BL + (size_t)b * NCAP * IN_CAPS + j;
    float v[16];
    float m = -1e30f;
#pragma unroll
    for (int i = 0; i < 16; ++i) {
        v[i] = p[(size_t)i * IN_CAPS];
        m = fmaxf(m, v[i]);
    }
    float s = 0.f;
#pragma unroll
    for (int i = 0; i < 16; ++i) {
        v[i] = __expf(v[i] - m);
        s += v[i];
    }
    const float inv = 1.0f / s;
#pragma unroll
    for (int i = 0; i < 16; ++i) p[(size_t)i * IN_CAPS] = v[i] * inv;
}

// ---------------------------------------------------------------------------
extern "C" void kernel_launch(void* const* d_in, const int* in_sizes, int n_in,
                              void* d_out, int out_size, void* d_ws, size_t ws_size,
                              hipStream_t stream) {
    float* OutC = (float*)d_out; // [64][16][64] fp32

    const size_t u_bytes = (size_t)BATCH * NCAP * IN_CAPS * DCAP * sizeof(bf16); // 64 MiB
    const size_t xb_bytes = (size_t)GM * GK * sizeof(bf16);                      // 48 MiB
    const size_t wt_bytes = (size_t)GN * GK * sizeof(bf16);                      // 1.5 MiB
    const size_t bl_bytes = (size_t)BATCH * NCAP * IN_CAPS * sizeof(float);      // 2 MiB
    char* ws = (char*)d_ws;

    const size_t need_big = u_bytes + xb_bytes + wt_bytes + bl_bytes + 256;
    const size_t need_small = u_bytes + wt_bytes + bl_bytes + 256;

    bf16* U = (bf16*)ws;
    bf16* Wt;
    float* BL;
    int* flag;

    if (ws_size >= need_big) {
        bf16* Xb = (bf16*)(ws + u_bytes);
        Wt = (bf16*)(ws + u_bytes + xb_bytes);
        BL = (float*)(ws + u_bytes + xb_bytes + wt_bytes);
        flag = (int*)(ws + u_bytes + xb_bytes + wt_bytes + bl_bytes);

        k_detect<<<1, 64, 0, stream>>>((const uint32_t*)d_in[0], flag);
        k_convX<bf16><<<GM * GK / (256 * 8), 256, 0, stream>>>(
            (const bf16*)d_in[0], Xb, flag, 1);
        k_convX<float><<<GM * GK / (256 * 8), 256, 0, stream>>>(
            (const float*)d_in[0], Xb, flag, 0);
        k_transW<bf16><<<dim3(GK / 32, GN / 32), dim3(32, 8), 0, stream>>>(
            (const bf16*)d_in[1], Wt, flag, 1);
        k_transW<float><<<dim3(GK / 32, GN / 32), dim3(32, 8), 0, stream>>>(
            (const float*)d_in[1], Wt, flag, 0);
        k_gemm_async<<<dim3(GM / 128, GN / 128), 256, 0, stream>>>(Xb, Wt, U);
    } else if (ws_size >= need_small) {
        Wt = (bf16*)(ws + u_bytes);
        BL = (float*)(ws + u_bytes + wt_bytes);
        flag = (int*)(ws + u_bytes + wt_bytes + bl_bytes);

        k_detect<<<1, 64, 0, stream>>>((const uint32_t*)d_in[0], flag);
        k_transW<bf16><<<dim3(GK / 32, GN / 32), dim3(32, 8), 0, stream>>>(
            (const bf16*)d_in[1], Wt, flag, 1);
        k_transW<float><<<dim3(GK / 32, GN / 32), dim3(32, 8), 0, stream>>>(
            (const float*)d_in[1], Wt, flag, 0);
        k_gemm_inline<bf16><<<dim3(GM / 128, GN / 128), 256, 0, stream>>>(
            (const bf16*)d_in[0], Wt, U, flag, 1);
        k_gemm_inline<float><<<dim3(GM / 128, GN / 128), 256, 0, stream>>>(
            (const float*)d_in[0], Wt, U, flag, 0);
    } else {
        return;
    }

    // routing: 3 fused passes + 2 softmaxes
    k_route<<<BATCH * NCAP, 256, 0, stream>>>(U, BL, OutC, 0);
    k_softmax<<<BATCH * IN_CAPS / 256, 256, 0, stream>>>(BL);
    k_route<<<BATCH * NCAP, 256, 0, stream>>>(U, BL, OutC, 1);
    k_softmax<<<BATCH * IN_CAPS / 256, 256, 0, stream>>>(BL);
    k_route<<<BATCH * NCAP, 256, 0, stream>>>(U, BL, OutC, 2);
}

// Round 6
// 277.718 us; speedup vs baseline: 1.0760x; 1.0760x over previous
//
#include <hip/hip_runtime.h>
#include <hip/hip_bf16.h>
#include <stdint.h>

// Problem constants
#define BATCH 64
#define IN_CAPS 512          // In (input capsules)
#define NCAP 16              // num_capsule
#define DCAP 64              // dim_capsule
#define GN (NCAP * DCAP)     // 1024
#define GM (BATCH * IN_CAPS) // 32768
#define GK 768               // input feature dim (K)

typedef __bf16 bf16;
typedef __attribute__((ext_vector_type(8))) __bf16 bf16x8;
typedef __attribute__((ext_vector_type(4))) __bf16 bf16x4;
typedef __attribute__((ext_vector_type(4))) float f32x4;

// async global->LDS 16B copy (wave-uniform LDS base + lane*16)
__device__ inline void async16(const bf16* g, bf16* l) {
    __builtin_amdgcn_global_load_lds(
        (__attribute__((address_space(1))) void*)g,
        (__attribute__((address_space(3))) void*)l, 16, 0, 0);
}

// ---------------------------------------------------------------------------
// Kernel 1: X (fp32) -> bf16, pure-BW pre-convert for global_load_lds staging.
// ---------------------------------------------------------------------------
__global__ __launch_bounds__(256) void k_convX(const float* __restrict__ X,
                                               bf16* __restrict__ Xb) {
    const size_t i = ((size_t)blockIdx.x * 256 + threadIdx.x) * 8;
    const f32x4 a = *(const f32x4*)(X + i);
    const f32x4 b = *(const f32x4*)(X + i + 4);
    bf16x8 r;
    r[0] = (bf16)a[0]; r[1] = (bf16)a[1]; r[2] = (bf16)a[2]; r[3] = (bf16)a[3];
    r[4] = (bf16)b[0]; r[5] = (bf16)b[1]; r[6] = (bf16)b[2]; r[7] = (bf16)b[3];
    *(bf16x8*)(Xb + i) = r;
}

// ---------------------------------------------------------------------------
// Kernel 2: transpose W [768][1024] fp32 -> Wt [1024][768] bf16 (K-contig).
// ---------------------------------------------------------------------------
__global__ void k_transW(const float* __restrict__ W, bf16* __restrict__ Wt) {
    __shared__ bf16 t[32][33];
    const int k0 = blockIdx.x * 32;
    const int n0 = blockIdx.y * 32;
    const int tx = threadIdx.x, ty = threadIdx.y;
#pragma unroll
    for (int r = 0; r < 4; ++r)
        t[ty + r * 8][tx] = (bf16)W[(size_t)(k0 + ty + r * 8) * GN + n0 + tx];
    __syncthreads();
#pragma unroll
    for (int r = 0; r < 4; ++r)
        Wt[(size_t)(n0 + ty + r * 8) * GK + k0 + tx] = t[tx][ty + r * 8];
}

// ---------------------------------------------------------------------------
// Kernel 3a: MFMA GEMM, async global->LDS staging (validated round 5, kept
// byte-identical).  U: [b][cap][j][k] bf16  (b=m>>9, j=m&511, cap=n>>6, k=n&63)
// ---------------------------------------------------------------------------
__global__ __launch_bounds__(256) void k_gemm_async(const bf16* __restrict__ Xb,
                                                    const bf16* __restrict__ Wt,
                                                    bf16* __restrict__ U) {
    __shared__ bf16 sA[128 * 32];
    __shared__ bf16 sB[128 * 32];

    const int tid = threadIdx.x;
    const int lane = tid & 63;
    const int wave = tid >> 6;
    const int wm = wave >> 1, wn = wave & 1;
    const int m0 = blockIdx.x * 128;
    const int n0 = blockIdx.y * 128;

    const int c0 = wave * 2, c1 = wave * 2 + 1;
    const int rl = lane >> 2, cl = (lane & 3) * 8;
    const bf16* gA0 = Xb + (size_t)(m0 + c0 * 16 + rl) * GK + cl;
    const bf16* gA1 = Xb + (size_t)(m0 + c1 * 16 + rl) * GK + cl;
    const bf16* gB0 = Wt + (size_t)(n0 + c0 * 16 + rl) * GK + cl;
    const bf16* gB1 = Wt + (size_t)(n0 + c1 * 16 + rl) * GK + cl;
    bf16* lA0 = sA + c0 * 512;
    bf16* lA1 = sA + c1 * 512;
    bf16* lB0 = sB + c0 * 512;
    bf16* lB1 = sB + c1 * 512;

    f32x4 acc[4][4] = {};
    const int fr = lane & 15;
    const int fq = lane >> 4;

    for (int kt = 0; kt < GK / 32; ++kt) {
        __syncthreads();
        async16(gA0, lA0);
        async16(gA1, lA1);
        async16(gB0, lB0);
        async16(gB1, lB1);
        gA0 += 32; gA1 += 32; gB0 += 32; gB1 += 32;
        __syncthreads();

        bf16x8 af[4], bfr[4];
#pragma unroll
        for (int mi = 0; mi < 4; ++mi)
            af[mi] = *(const bf16x8*)(sA + (wm * 64 + mi * 16 + fr) * 32 + fq * 8);
#pragma unroll
        for (int ni = 0; ni < 4; ++ni)
            bfr[ni] = *(const bf16x8*)(sB + (wn * 64 + ni * 16 + fr) * 32 + fq * 8);
#pragma unroll
        for (int mi = 0; mi < 4; ++mi)
#pragma unroll
            for (int ni = 0; ni < 4; ++ni)
                acc[mi][ni] = __builtin_amdgcn_mfma_f32_16x16x32_bf16(
                    af[mi], bfr[ni], acc[mi][ni], 0, 0, 0);
    }

#pragma unroll
    for (int mi = 0; mi < 4; ++mi) {
#pragma unroll
        for (int ni = 0; ni < 4; ++ni) {
#pragma unroll
            for (int r = 0; r < 4; ++r) {
                const int m = m0 + wm * 64 + mi * 16 + fq * 4 + r;
                const int n = n0 + wn * 64 + ni * 16 + fr;
                const int bb = m >> 9, j = m & 511;
                const int ci = n >> 6, k = n & 63;
                U[(((size_t)(bb * NCAP + ci)) * IN_CAPS + j) * DCAP + k] =
                    (bf16)acc[mi][ni][r];
            }
        }
    }
}

// ---------------------------------------------------------------------------
// Kernel 3b: fallback GEMM (round-4 validated, inline conversion) — only if
// ws can't hold Xb.
// ---------------------------------------------------------------------------
__global__ __launch_bounds__(256) void k_gemm_inline(const float* __restrict__ X,
                                                     const bf16* __restrict__ Wt,
                                                     bf16* __restrict__ U) {
    __shared__ bf16 sA[128 * 32];
    __shared__ bf16 sB[128 * 32];
    const int tid = threadIdx.x;
    const int lane = tid & 63;
    const int wave = tid >> 6;
    const int wm = wave >> 1, wn = wave & 1;
    const int m0 = blockIdx.x * 128;
    const int n0 = blockIdx.y * 128;
    const int srow = tid >> 2;
    const int scol = (tid & 3) * 8;
    f32x4 acc[4][4] = {};
    const int fr = lane & 15;
    const int fq = lane >> 4;
    for (int kt = 0; kt < GK / 32; ++kt) {
        const int kb = kt * 32;
        bf16x8 a0, a1, b0, b1;
        {
            const float* p = X + (size_t)(m0 + srow) * GK + kb + scol;
            const f32x4 x0 = *(const f32x4*)p, x1 = *(const f32x4*)(p + 4);
            const float* q = X + (size_t)(m0 + srow + 64) * GK + kb + scol;
            const f32x4 y0 = *(const f32x4*)q, y1 = *(const f32x4*)(q + 4);
#pragma unroll
            for (int c = 0; c < 4; ++c) {
                a0[c] = (bf16)x0[c]; a0[c + 4] = (bf16)x1[c];
                a1[c] = (bf16)y0[c]; a1[c + 4] = (bf16)y1[c];
            }
        }
        b0 = *(const bf16x8*)(Wt + (size_t)(n0 + srow) * GK + kb + scol);
        b1 = *(const bf16x8*)(Wt + (size_t)(n0 + srow + 64) * GK + kb + scol);
        __syncthreads();
        *(bf16x8*)(sA + srow * 32 + scol) = a0;
        *(bf16x8*)(sA + (srow + 64) * 32 + scol) = a1;
        *(bf16x8*)(sB + srow * 32 + scol) = b0;
        *(bf16x8*)(sB + (srow + 64) * 32 + scol) = b1;
        __syncthreads();
        bf16x8 af[4], bfr[4];
#pragma unroll
        for (int mi = 0; mi < 4; ++mi)
            af[mi] = *(const bf16x8*)(sA + (wm * 64 + mi * 16 + fr) * 32 + fq * 8);
#pragma unroll
        for (int ni = 0; ni < 4; ++ni)
            bfr[ni] = *(const bf16x8*)(sB + (wn * 64 + ni * 16 + fr) * 32 + fq * 8);
#pragma unroll
        for (int mi = 0; mi < 4; ++mi)
#pragma unroll
            for (int ni = 0; ni < 4; ++ni)
                acc[mi][ni] = __builtin_amdgcn_mfma_f32_16x16x32_bf16(
                    af[mi], bfr[ni], acc[mi][ni], 0, 0, 0);
    }
#pragma unroll
    for (int mi = 0; mi < 4; ++mi) {
#pragma unroll
        for (int ni = 0; ni < 4; ++ni) {
#pragma unroll
            for (int r = 0; r < 4; ++r) {
                const int m = m0 + wm * 64 + mi * 16 + fq * 4 + r;
                const int n = n0 + wn * 64 + ni * 16 + fr;
                const int bb = m >> 9, j = m & 511;
                const int ci = n >> 6, k = n & 63;
                U[(((size_t)(bb * NCAP + ci)) * IN_CAPS + j) * DCAP + k] =
                    (bf16)acc[mi][ni][r];
            }
        }
    }
}

// ---------------------------------------------------------------------------
// Kernel 4: routing pass v2 — fused softmax + out + squash + logits.
// Block per (b,cap), 256 threads. NO big LDS staging: phase A streams U with
// perfect 16B/lane coalescing (thread t -> byte offset tid*16 within slice);
// phase B re-reads the same 64 KiB (L1/L2/L3-hot). LDS ~11 KiB -> high occ.
//   mode 0: c = 1/16 (softmax of zeros), write logits
//   mode 1: c = softmax(BL over capsule axis), write logits
//   mode 2: c = softmax(BL), write final output, no logits
// ---------------------------------------------------------------------------
__global__ __launch_bounds__(256) void k_route(const bf16* __restrict__ U,
                                               float* __restrict__ BL,
                                               float* __restrict__ OutC,
                                               int mode) {
    __shared__ float sc[IN_CAPS];  // 2 KiB: c[j]
    __shared__ float red[32][64];  // 8 KiB: j-group partials per k
    __shared__ float sout[64];     // 256 B
    const int bi = blockIdx.x;          // b*16 + cap
    const int b = bi >> 4, cap = bi & 15;
    const int tid = threadIdx.x;
    const size_t ubase = (size_t)bi * IN_CAPS * DCAP;

    // --- fused softmax over the 16-capsule axis -> c[j] for own capsule ---
    if (mode == 0) {
        sc[tid] = 0.0625f;
        sc[tid + 256] = 0.0625f;
    } else {
#pragma unroll
        for (int h = 0; h < 2; ++h) {
            const int j = tid + h * 256;
            const float* p = BL + (size_t)b * NCAP * IN_CAPS + j;
            float v[16], mx = -1e30f;
#pragma unroll
            for (int i = 0; i < 16; ++i) {
                v[i] = p[(size_t)i * IN_CAPS];
                mx = fmaxf(mx, v[i]);
            }
            float s = 0.f;
#pragma unroll
            for (int i = 0; i < 16; ++i) s += __expf(v[i] - mx);
            sc[j] = __expf(v[cap] - mx) / s;
        }
    }
    __syncthreads();

    const int g = tid & 7;   // k-octet: k = g*8 .. g*8+7
    const int jr = tid >> 3; // j-row group 0..31

    // --- phase A: acc[k-octet] = sum_j c[j] * u[j][k], coalesced 16B/lane ---
    float acc[8] = {};
#pragma unroll
    for (int it = 0; it < 16; ++it) {
        const int j = it * 32 + jr;
        const bf16x8 v = *(const bf16x8*)(U + ubase + (size_t)it * 2048 + tid * 8);
        const float cv = sc[j];
#pragma unroll
        for (int c = 0; c < 8; ++c) acc[c] += cv * (float)v[c];
    }
    *(f32x4*)(&red[jr][g * 8]) = f32x4{acc[0], acc[1], acc[2], acc[3]};
    *(f32x4*)(&red[jr][g * 8 + 4]) = f32x4{acc[4], acc[5], acc[6], acc[7]};
    __syncthreads();

    // --- reduce 32 j-groups per k, squash (wave 0, lane = k) ---
    if (tid < 64) {
        float s = 0.f;
#pragma unroll
        for (int r = 0; r < 32; ++r) s += red[r][tid];
        float ss = s * s;
#pragma unroll
        for (int off = 32; off >= 1; off >>= 1) ss += __shfl_xor(ss, off);
        const float val = s * rsqrtf(ss + 1e-7f);
        sout[tid] = val;
        if (mode == 2) OutC[(size_t)bi * DCAP + tid] = val;
    }
    if (mode == 2) return; // block-uniform
    __syncthreads();

    // --- phase B: logits bl[j] = <out, u[j]>, re-read U (cache-hot) ---
    const f32x4 o0 = *(const f32x4*)(sout + g * 8);
    const f32x4 o1 = *(const f32x4*)(sout + g * 8 + 4);
#pragma unroll
    for (int it = 0; it < 16; ++it) {
        const int j = it * 32 + jr;
        const bf16x8 v = *(const bf16x8*)(U + ubase + (size_t)it * 2048 + tid * 8);
        float p = o0[0] * (float)v[0] + o0[1] * (float)v[1] +
                  o0[2] * (float)v[2] + o0[3] * (float)v[3] +
                  o1[0] * (float)v[4] + o1[1] * (float)v[5] +
                  o1[2] * (float)v[6] + o1[3] * (float)v[7];
        p += __shfl_xor(p, 1); // reduce over k-octets g (low 3 lane bits)
        p += __shfl_xor(p, 2);
        p += __shfl_xor(p, 4);
        if (g == 0) BL[((size_t)b * NCAP + cap) * IN_CAPS + j] = p;
    }
}

// ---------------------------------------------------------------------------
extern "C" void kernel_launch(void* const* d_in, const int* in_sizes, int n_in,
                              void* d_out, int out_size, void* d_ws, size_t ws_size,
                              hipStream_t stream) {
    const float* X = (const float*)d_in[0]; // [64][512][768] fp32
    const float* W = (const float*)d_in[1]; // [768][1024] fp32
    float* OutC = (float*)d_out;            // [64][16][64] fp32

    const size_t u_bytes = (size_t)BATCH * NCAP * IN_CAPS * DCAP * sizeof(bf16); // 64 MiB
    const size_t xb_bytes = (size_t)GM * GK * sizeof(bf16);                      // 48 MiB
    const size_t wt_bytes = (size_t)GN * GK * sizeof(bf16);                      // 1.5 MiB
    const size_t bl_bytes = (size_t)BATCH * NCAP * IN_CAPS * sizeof(float);      // 2 MiB
    char* ws = (char*)d_ws;

    const size_t need_big = u_bytes + xb_bytes + wt_bytes + bl_bytes;
    const size_t need_small = u_bytes + wt_bytes + bl_bytes;

    bf16* U = (bf16*)ws;
    bf16* Wt;
    float* BL;

    if (ws_size >= need_big) {
        bf16* Xb = (bf16*)(ws + u_bytes);
        Wt = (bf16*)(ws + u_bytes + xb_bytes);
        BL = (float*)(ws + u_bytes + xb_bytes + wt_bytes);
        k_convX<<<GM * GK / (256 * 8), 256, 0, stream>>>(X, Xb);
        k_transW<<<dim3(GK / 32, GN / 32), dim3(32, 8), 0, stream>>>(W, Wt);
        k_gemm_async<<<dim3(GM / 128, GN / 128), 256, 0, stream>>>(Xb, Wt, U);
    } else if (ws_size >= need_small) {
        Wt = (bf16*)(ws + u_bytes);
        BL = (float*)(ws + u_bytes + wt_bytes);
        k_transW<<<dim3(GK / 32, GN / 32), dim3(32, 8), 0, stream>>>(W, Wt);
        k_gemm_inline<<<dim3(GM / 128, GN / 128), 256, 0, stream>>>(X, Wt, U);
    } else {
        return;
    }

    // routing: 3 fused passes (softmax folded in)
    k_route<<<BATCH * NCAP, 256, 0, stream>>>(U, BL, OutC, 0);
    k_route<<<BATCH * NCAP, 256, 0, stream>>>(U, BL, OutC, 1);
    k_route<<<BATCH * NCAP, 256, 0, stream>>>(U, BL, OutC, 2);
}